// Round 7
// baseline (88.864 us; speedup 1.0000x reference)
//
#include <hip/hip_runtime.h>
#include <hip/hip_bf16.h>
#include <stdint.h>

#define S_SCALE 30.0f
#define S_LOG2E 43.2808512266689f   /* 30 * log2(e) */
#define N_ROWS 8192
#define D_DIM 256
#define C_CLS 10000
#define C_PAD 10240   /* 40 * 256 */
#define NCB 8

typedef __attribute__((ext_vector_type(8))) short short8;
typedef __attribute__((ext_vector_type(4))) float f32x4;
typedef __attribute__((ext_vector_type(4))) unsigned short us4;

static __device__ __forceinline__ unsigned short f2bf(float f) {
  union { float f; unsigned u; } a; a.f = f;
  unsigned r = a.u + 0x7fffu + ((a.u >> 16) & 1u);
  return (unsigned short)(r >> 16);
}

static __device__ __forceinline__ void gl16(const void* g, void* l) {
  __builtin_amdgcn_global_load_lds(
      (const __attribute__((address_space(1))) void*)g,
      (__attribute__((address_space(3))) void*)l, 16, 0, 0);
}

// 16-lane (DPP-row) sum, VALU pipe only; all lanes receive the group sum.
static __device__ __forceinline__ float row_sum16(float v) {
  union { float f; int i; } u, w;
  u.f = v;
  w.i = __builtin_amdgcn_update_dpp(0, u.i, 0xB1, 0xF, 0xF, true);  u.f += w.f; // lane^1
  w.i = __builtin_amdgcn_update_dpp(0, u.i, 0x4E, 0xF, 0xF, true);  u.f += w.f; // lane^2
  w.i = __builtin_amdgcn_update_dpp(0, u.i, 0x141, 0xF, 0xF, true); u.f += w.f; // half-mirror
  w.i = __builtin_amdgcn_update_dpp(0, u.i, 0x140, 0xF, 0xF, true); u.f += w.f; // row-mirror
  return u.f;
}

// ------- fused: row L2-normalize -> bf16, exact fp32 target logit -------
__global__ __launch_bounds__(256) void k_normtgt(const float* __restrict__ x,
                                                 const float* __restrict__ W,
                                                 const int* __restrict__ target,
                                                 unsigned short* __restrict__ xnb,
                                                 float* __restrict__ tgt) {
  int row = blockIdx.x * 4 + (threadIdx.x >> 6);
  int l = threadIdx.x & 63;
  const float4 v = *(const float4*)(x + (size_t)row * D_DIM + l * 4);
  float ss = v.x * v.x + v.y * v.y + v.z * v.z + v.w * v.w;
#pragma unroll
  for (int m = 1; m < 64; m <<= 1) ss += __shfl_xor(ss, m, 64);
  float rn = 1.0f / sqrtf(ss);
  us4 o;
  o.x = f2bf(v.x * rn); o.y = f2bf(v.y * rn);
  o.z = f2bf(v.z * rn); o.w = f2bf(v.w * rn);
  *(us4*)(xnb + (size_t)row * D_DIM + l * 4) = o;
  int tc = target[row];
  const float4 b = *(const float4*)(W + (size_t)tc * D_DIM + l * 4);
  float s = v.x * b.x + v.y * b.y + v.z * b.z + v.w * b.w;
#pragma unroll
  for (int m = 1; m < 64; m <<= 1) s += __shfl_xor(s, m, 64);
  if (l == 0) tgt[row] = s * rn;
}

// ---------------- W fp32 -> bf16, zero-pad rows to C_PAD ----------------
__global__ __launch_bounds__(256) void k_convw(const float* __restrict__ W,
                                               unsigned short* __restrict__ Wb) {
  int idx = blockIdx.x * 256 + threadIdx.x;   // 8 elems per thread
  size_t base = (size_t)idx * 8;
  int row = (int)(base >> 8);
  us4 o0 = {0, 0, 0, 0}, o1 = {0, 0, 0, 0};
  if (row < C_CLS) {
    const float4 a = *(const float4*)(W + base);
    const float4 b = *(const float4*)(W + base + 4);
    o0.x = f2bf(a.x); o0.y = f2bf(a.y); o0.z = f2bf(a.z); o0.w = f2bf(a.w);
    o1.x = f2bf(b.x); o1.y = f2bf(b.y); o1.z = f2bf(b.z); o1.w = f2bf(b.w);
  }
  *(us4*)(Wb + base) = o0;
  *(us4*)(Wb + base + 4) = o1;
}

// ------- persistent fused bf16 GEMM + exp-sum epilogue, counted-vmcnt pipeline ----
// 256 blocks (1/CU), fixed br, 5 consecutive bc tiles = 40 K-tiles of BK=32.
// 4 LDS slots (32 KB) -> stage 2 K-tiles ahead; per-K-tile wait = vmcnt(4), never 0.
// 2 phases/K-tile, 16 MFMA each (16x16x32). Epilogue: pure-VALU exp2 accumulation
// into 32 register accumulators; single DPP reduce + store at the end.
// T2 swizzle: slot ^= row&3 (pre-swizzled global source, linear gl16 dest).
__global__ __launch_bounds__(512, 2) void k_gemm(const unsigned short* __restrict__ xnb,
                                                 const unsigned short* __restrict__ Wb,
                                                 float* __restrict__ partials) {
  __shared__ __align__(16) char lds[135168];
  // 4 slots of 32 KB (A @ +0, B @ +16384); rowsum @ 131072 (4 KB)
  const int b = blockIdx.x;
  const int x8 = b & 7, q = b >> 3;
  const int br = (x8 >> 2) * 16 + (q & 15);
  const int bc0 = (x8 & 3) * 10 + (q >> 4) * 5;
  const int cc = (x8 & 3) * 2 + (q >> 4);            // 0..7 partial-chunk id
  const int t = threadIdx.x;
  const int w = t >> 6, l = t & 63;
  const int wr = w >> 2, wc = w & 3;                 // 2M x 4N waves
  const int lr = l & 15, lk = l >> 4;
  const char* Ag = (const char*)xnb + (size_t)br * 256 * 512;   // 512 B/row
  const char* Wb8 = (const char*)Wb;

  f32x4 acc[8][4];
#pragma unroll
  for (int m = 0; m < 8; m++)
#pragma unroll
    for (int n = 0; n < 4; n++) acc[m][n] = (f32x4){0.f, 0.f, 0.f, 0.f};
  float rsacc[8][4];
#pragma unroll
  for (int m = 0; m < 8; m++)
#pragma unroll
    for (int j = 0; j < 4; j++) rsacc[m][j] = 0.f;

  // stage part (0/1) of K-tile into slot: 2 gl16/thread (A 8KB + B 8KB)
  auto stagePart = [&](int dslot, const char* BgS, int ko, int part) {
    int p = part * 8192 + t * 16;
    int row = p >> 6;                       // 64 B per row (BK=32 bf16)
    int su = ((p >> 4) & 3) ^ (row & 3);    // pre-swizzled source slot
    size_t go = (size_t)row * 512 + (size_t)ko + (size_t)(su << 4);
    char* base = lds + dslot * 32768;
    int lo = part * 8192 + w * 1024;        // wave-uniform LDS dest
    gl16(Ag + go, base + lo);
    gl16(BgS + go, base + 16384 + lo);
  };

  auto ldA = [&](const char* sb, int fm) -> short8 {
    int row = wr * 128 + fm * 16 + lr;
    int byte = row * 64 + ((lk ^ (row & 3)) << 4);
    return *(const short8*)(sb + byte);
  };
  auto ldB = [&](const char* sb, int fn) -> short8 {
    int row = wc * 64 + fn * 16 + lr;
    int byte = 16384 + row * 64 + ((lk ^ (row & 3)) << 4);
    return *(const short8*)(sb + byte);
  };

  // prologue: stage K-tiles 0 and 1; wait for tile 0 only (counted).
  {
    const char* B0 = Wb8 + (size_t)bc0 * 131072;
    stagePart(0, B0, 0, 0);  stagePart(0, B0, 0, 1);
    stagePart(1, B0, 64, 0); stagePart(1, B0, 64, 1);
    asm volatile("s_waitcnt vmcnt(4)" ::: "memory");
    __builtin_amdgcn_sched_barrier(0);
    __builtin_amdgcn_s_barrier();
  }

  for (int tt = 0; tt < 5; ++tt) {
#pragma unroll
    for (int k8 = 0; k8 < 8; ++k8) {
      const char* sb = lds + (k8 & 3) * 32768;      // (tt*8+k8)&3 == k8&3
      const int ktg = tt * 8 + k8 + 2;              // stage target
      const bool doSt = (ktg < 40);
      const int nslot = (k8 + 2) & 3;
      const int ko = ((k8 + 2) & 7) * 64;           // ktg&7 independent of tt
      const char* BgS = Wb8 + (size_t)(bc0 + tt + ((k8 + 2) >> 3)) * 131072;

      short8 bfr[4], afr[4];
      // ---- phase 0: read B frags + A frags 0..3, stage part 0, MFMA m0..3
#pragma unroll
      for (int n = 0; n < 4; ++n) bfr[n] = ldB(sb, n);
#pragma unroll
      for (int i = 0; i < 4; ++i) afr[i] = ldA(sb, i);
      if (doSt) stagePart(nslot, BgS, ko, 0);
      __builtin_amdgcn_s_barrier();
      asm volatile("s_waitcnt lgkmcnt(0)" ::: "memory");
      __builtin_amdgcn_sched_barrier(0);
      __builtin_amdgcn_s_setprio(1);
#pragma unroll
      for (int i = 0; i < 4; ++i)
#pragma unroll
        for (int n = 0; n < 4; ++n)
          acc[i][n] = __builtin_amdgcn_mfma_f32_16x16x32_bf16(afr[i], bfr[n], acc[i][n], 0, 0, 0);
      __builtin_amdgcn_s_setprio(0);
      __builtin_amdgcn_sched_barrier(0);
      __builtin_amdgcn_s_barrier();

      // ---- phase 1: read A frags 4..7, stage part 1, MFMA m4..7
#pragma unroll
      for (int i = 0; i < 4; ++i) afr[i] = ldA(sb, 4 + i);
      if (doSt) stagePart(nslot, BgS, ko, 1);
      __builtin_amdgcn_s_barrier();
      asm volatile("s_waitcnt lgkmcnt(0)" ::: "memory");
      __builtin_amdgcn_sched_barrier(0);
      __builtin_amdgcn_s_setprio(1);
#pragma unroll
      for (int i = 0; i < 4; ++i)
#pragma unroll
        for (int n = 0; n < 4; ++n)
          acc[4 + i][n] = __builtin_amdgcn_mfma_f32_16x16x32_bf16(afr[i], bfr[n], acc[4 + i][n], 0, 0, 0);
      __builtin_amdgcn_s_setprio(0);
      __builtin_amdgcn_sched_barrier(0);
      {
        const int ktc = tt * 8 + k8;
        if (ktc < 38) {
          asm volatile("s_waitcnt vmcnt(4)" ::: "memory");   // kt+1 done, kt+2 in flight
        } else if (ktc == 38) {
          asm volatile("s_waitcnt vmcnt(0)" ::: "memory");   // tail drain
        }
        __builtin_amdgcn_sched_barrier(0);
      }
      __builtin_amdgcn_s_barrier();
    }

    // ---- per-bc-tile epilogue: pure VALU. exp2 accumulate, zero acc. ----
    // 16x16 C/D: col = lane&15, row = (lane>>4)*4 + j.
    {
      const int bc = bc0 + tt;
#pragma unroll
      for (int m = 0; m < 8; ++m) {
#pragma unroll
        for (int n = 0; n < 4; ++n) {
          int col = bc * 256 + wc * 64 + n * 16 + lr;
          bool ok = (col < C_CLS);
#pragma unroll
          for (int j = 0; j < 4; ++j)
            rsacc[m][j] += ok ? __builtin_amdgcn_exp2f(acc[m][n][j] * S_LOG2E) : 0.f;
          acc[m][n] = (f32x4){0.f, 0.f, 0.f, 0.f};
        }
      }
    }
  }

  // ---- final: DPP 16-lane reduce, one LDS round, one coalesced store ----
  float* rsum = (float*)(lds + 131072);   // [4 wc][256 rows]
#pragma unroll
  for (int m = 0; m < 8; ++m)
#pragma unroll
    for (int j = 0; j < 4; ++j) rsacc[m][j] = row_sum16(rsacc[m][j]);
  if (lr == 0) {
#pragma unroll
    for (int m = 0; m < 8; ++m)
#pragma unroll
      for (int j = 0; j < 4; ++j)
        rsum[wc * 256 + wr * 128 + m * 16 + lk * 4 + j] = rsacc[m][j];
  }
  __syncthreads();
  if (t < 256) {
    float sv = rsum[t] + rsum[256 + t] + rsum[512 + t] + rsum[768 + t];
    partials[(size_t)cc * N_ROWS + (size_t)br * 256 + t] = sv;
  }
}

// ---------------- per-row loss + block partial sums ----------------
__global__ __launch_bounds__(256) void k_loss1(const float* __restrict__ partials,
                                               const float* __restrict__ tgt,
                                               float* __restrict__ bsum) {
  __shared__ float wsum[4];
  int i = blockIdx.x * 256 + threadIdx.x;
  const float* p = partials + i;
  float s = 0.f;
#pragma unroll
  for (int j = 0; j < NCB; ++j) s += p[(size_t)j * N_ROWS];
  float tl = tgt[i];
  float tcv = fminf(fmaxf(tl, -1.0f + 1e-7f), 1.0f - 1e-7f);
  const float cm = 0.95533648912560601964f;   // cos(0.3)
  const float sm = 0.29552020666133957510f;   // sin(0.3)
  float num = S_SCALE * (tcv * cm - sqrtf(fmaxf(1.0f - tcv * tcv, 0.f)) * sm);
  float sum_excl = s - __expf(S_SCALE * tl);
  float denom = __expf(num) + sum_excl;
  float L = num - __logf(denom);
#pragma unroll
  for (int m = 1; m < 64; m <<= 1) L += __shfl_xor(L, m, 64);
  int l = threadIdx.x & 63, w = threadIdx.x >> 6;
  if (l == 0) wsum[w] = L;
  __syncthreads();
  if (threadIdx.x == 0) bsum[blockIdx.x] = wsum[0] + wsum[1] + wsum[2] + wsum[3];
}

__global__ void k_loss2(const float* __restrict__ bsum, float* __restrict__ out) {
  float s = 0.f;
  for (int i = 0; i < 32; ++i) s += bsum[i];
  out[0] = -s / (float)N_ROWS;
}

// ---------------- launch ----------------
extern "C" void kernel_launch(void* const* d_in, const int* in_sizes, int n_in,
                              void* d_out, int out_size, void* d_ws, size_t ws_size,
                              hipStream_t stream) {
  const float* x = (const float*)d_in[0];
  const float* W = (const float*)d_in[1];
  const int* target = (const int*)d_in[2];
  float* out = (float*)d_out;
  char* ws = (char*)d_ws;

  unsigned short* xnb = (unsigned short*)(ws);              // 8192*256*2   = 4,194,304
  unsigned short* Wb = (unsigned short*)(ws + 4194304);     // 10240*256*2  = 5,242,880
  float* tgt = (float*)(ws + 9437184);                      // 8192*4
  float* partials = (float*)(ws + 9469952);                 // 8*8192*4     = 262,144
  float* bsum = (float*)(ws + 9732096);                     // 32*4

  k_normtgt<<<2048, 256, 0, stream>>>(x, W, target, xnb, tgt);
  k_convw<<<1280, 256, 0, stream>>>(W, Wb);
  k_gemm<<<256, 512, 0, stream>>>(xnb, Wb, partials);
  k_loss1<<<32, 256, 0, stream>>>(partials, tgt, bsum);
  k_loss2<<<1, 1, 0, stream>>>(bsum, out);
}